// Round 1
// baseline (113.378 us; speedup 1.0000x reference)
//
#include <hip/hip_runtime.h>
#include <math.h>

// TM-score, single fused kernel. S=1024 samples, L=4096 residues, fp32.
// One block per sample, 256 threads, 16 residues/thread.
// v2 (single-pass): whole 48KB pred sample async-staged to LDS ONCE via
// global_load_lds (12 x 16B per thread, deep pipeline), one barrier.
// Phase 1 (covariance sums) and Phase 2 (aligned distances) both read LDS;
// true/mask re-read from L2 in phase 2 (48KB/16KB, resident). Mask carried
// between phases as a 16-bit register. 3 barriers total (was 9).
// QCP solve unchanged: fp64 Newton on quartic char poly, eigvec via adjugate.

#define NS        1024
#define NL        4096
#define TPB       256

__device__ __forceinline__ float waveReduceSum(float v) {
    #pragma unroll
    for (int off = 32; off > 0; off >>= 1)
        v += __shfl_down(v, off, 64);
    return v;
}

__device__ __forceinline__ double det3(const double B[4][4],
                                       int r0, int r1, int r2,
                                       int c0, int c1, int c2) {
    return B[r0][c0]*(B[r1][c1]*B[r2][c2] - B[r1][c2]*B[r2][c1])
         - B[r0][c1]*(B[r1][c0]*B[r2][c2] - B[r1][c2]*B[r2][c0])
         + B[r0][c2]*(B[r1][c0]*B[r2][c1] - B[r1][c1]*B[r2][c0]);
}

__device__ __forceinline__ void async_copy16(void* lds_dst, const void* g_src) {
    __builtin_amdgcn_global_load_lds(
        (const __attribute__((address_space(1))) void*)g_src,
        (__attribute__((address_space(3))) void*)lds_dst,
        16, 0, 0);
}

__global__ __launch_bounds__(TPB, 3) void tm_fused(
    const float* __restrict__ pred, const float* __restrict__ tru,
    const int* __restrict__ mask, float* __restrict__ out)
{
    const int s    = blockIdx.x;
    const int tid  = threadIdx.x;
    const int wave = tid >> 6, lane = tid & 63;
    const float* ps = pred + (size_t)s * NL * 3;

    __shared__ float ldsP[NL * 3];      // 48 KB: entire pred sample
    __shared__ float sred[4][18];
    __shared__ float sfin[4];

    // ---------------- async stage: pred sample -> LDS (once) ----------------
    // per wave: 768 float4 = 12 iterations x 64 lanes x 16B. LDS dest is
    // wave-uniform base; HW adds lane*16 (linear dest <-> linear source).
    const float4* gp4 = (const float4*)ps;
    float4* lp4 = (float4*)ldsP;
    #pragma unroll
    for (int j = 0; j < 12; ++j) {
        const int base = wave * 768 + j * 64;
        async_copy16((void*)(lp4 + base), (const void*)(gp4 + base + lane));
    }

    // Overlap staging latency: load mask now (L2-resident), pack to bits.
    unsigned mbits = 0;
    {
        #pragma unroll
        for (int k = 0; k < 4; ++k) {
            const int4 mi = *(const int4*)(mask + k * 1024 + tid * 4);
            if (mi.x) mbits |= 1u << (k * 4 + 0);
            if (mi.y) mbits |= 1u << (k * 4 + 1);
            if (mi.z) mbits |= 1u << (k * 4 + 2);
            if (mi.w) mbits |= 1u << (k * 4 + 3);
        }
    }

    __syncthreads();   // staging (and mask loads) complete

    // ---------------- Phase 1: covariance sums ----------------
    // acc: [0]=Lt [1..3]=St [4..6]=Sp [7..15]=C[i][j] [16]=Sum w|p|^2 [17]=Sum w|t|^2
    float acc[18];
    #pragma unroll
    for (int i = 0; i < 18; ++i) acc[i] = 0.f;

    const float4* gt4 = (const float4*)tru;
    #pragma unroll
    for (int k = 0; k < 4; ++k) {
        const float4* rp = (const float4*)&ldsP[k * 3072 + tid * 12];
        const float4 q0 = rp[0], q1 = rp[1], q2 = rp[2];
        const float4 u0 = gt4[k * 768 + tid * 3 + 0];
        const float4 u1 = gt4[k * 768 + tid * 3 + 1];
        const float4 u2 = gt4[k * 768 + tid * 3 + 2];

        const float px[4] = {q0.x, q0.w, q1.z, q2.y};
        const float py[4] = {q0.y, q1.x, q1.w, q2.z};
        const float pz[4] = {q0.z, q1.y, q2.x, q2.w};
        const float tx[4] = {u0.x, u0.w, u1.z, u2.y};
        const float ty[4] = {u0.y, u1.x, u1.w, u2.z};
        const float tz[4] = {u0.z, u1.y, u2.x, u2.w};

        #pragma unroll
        for (int r = 0; r < 4; ++r) {
            const float w = ((mbits >> (k * 4 + r)) & 1u) ? 1.f : 0.f;
            const float wpx = w * px[r], wpy = w * py[r], wpz = w * pz[r];
            acc[0] += w;
            acc[1] += w * tx[r]; acc[2] += w * ty[r]; acc[3] += w * tz[r];
            acc[4] += wpx; acc[5] += wpy; acc[6] += wpz;
            acc[7]  += wpx * tx[r]; acc[8]  += wpx * ty[r]; acc[9]  += wpx * tz[r];
            acc[10] += wpy * tx[r]; acc[11] += wpy * ty[r]; acc[12] += wpy * tz[r];
            acc[13] += wpz * tx[r]; acc[14] += wpz * ty[r]; acc[15] += wpz * tz[r];
            acc[16] += wpx * px[r] + wpy * py[r] + wpz * pz[r];
            acc[17] += w * (tx[r]*tx[r] + ty[r]*ty[r] + tz[r]*tz[r]);
        }
    }

    #pragma unroll
    for (int i = 0; i < 18; ++i) {
        float r = waveReduceSum(acc[i]);
        if (lane == 0) sred[wave][i] = r;
    }
    __syncthreads();

    // ---------------- QCP solve (all threads, identical data) ----------------
    double S[18];
    #pragma unroll
    for (int i = 0; i < 18; ++i)
        S[i] = (double)sred[0][i] + (double)sred[1][i]
             + (double)sred[2][i] + (double)sred[3][i];

    const double Lt = S[0], invLt = 1.0 / Lt;
    const double tmxd = S[1]*invLt, tmyd = S[2]*invLt, tmzd = S[3]*invLt;
    const double pmxd = S[4]*invLt, pmyd = S[5]*invLt, pmzd = S[6]*invLt;

    // scaled centered covariance HA = (C - Sp St^T / Lt) / Lt ; scaled Gram traces
    double HA[3][3];
    const double Sp[3] = {S[4], S[5], S[6]};
    const double St[3] = {S[1], S[2], S[3]};
    #pragma unroll
    for (int i = 0; i < 3; ++i)
        #pragma unroll
        for (int j = 0; j < 3; ++j)
            HA[i][j] = (S[7 + i*3 + j] - Sp[i]*St[j]*invLt) * invLt;
    const double gA = (S[16] - (Sp[0]*Sp[0]+Sp[1]*Sp[1]+Sp[2]*Sp[2])*invLt) * invLt;
    const double gB = (S[17] - (St[0]*St[0]+St[1]*St[1]+St[2]*St[2])*invLt) * invLt;

    const double Sxx=HA[0][0], Sxy=HA[0][1], Sxz=HA[0][2];
    const double Syx=HA[1][0], Syy=HA[1][1], Syz=HA[1][2];
    const double Szx=HA[2][0], Szy=HA[2][1], Szz=HA[2][2];
    double K[4][4] = {
      { Sxx+Syy+Szz, Syz-Szy,      Szx-Sxz,      Sxy-Syx      },
      { Syz-Szy,     Sxx-Syy-Szz,  Sxy+Syx,      Szx+Sxz      },
      { Szx-Sxz,     Sxy+Syx,      Syy-Sxx-Szz,  Syz+Szy      },
      { Sxy-Syx,     Szx+Sxz,      Syz+Szy,      Szz-Sxx-Syy  }
    };

    // char poly det(lam I - K) = lam^4 + E2 lam^2 - E3 lam + E4   (tr K = 0)
    double E2 = 0.0;
    #pragma unroll
    for (int i = 0; i < 4; ++i)
        #pragma unroll
        for (int j = 0; j < 4; ++j)
            if (j > i) E2 += K[i][i]*K[j][j] - K[i][j]*K[i][j];
    const double E3 = det3(K,1,2,3, 1,2,3) + det3(K,0,2,3, 0,2,3)
                    + det3(K,0,1,3, 0,1,3) + det3(K,0,1,2, 0,1,2);
    const double E4 = K[0][0]*det3(K,1,2,3, 1,2,3) - K[0][1]*det3(K,1,2,3, 0,2,3)
                    + K[0][2]*det3(K,1,2,3, 0,1,3) - K[0][3]*det3(K,1,2,3, 0,1,2);

    double lam = 0.5 * (gA + gB);          // upper bound on lambda_max
    #pragma unroll
    for (int it = 0; it < 8; ++it) {
        const double l2 = lam * lam;
        const double P  = ((l2 + E2) * lam - E3) * lam + E4;
        const double Pd = (4.0 * l2 + 2.0 * E2) * lam - E3;
        if (fabs(Pd) < 1e-300) break;
        lam -= P / Pd;
    }

    // eigenvector = best row of cofactor matrix of B = K - lam I
    #pragma unroll
    for (int i = 0; i < 4; ++i) K[i][i] -= lam;
    double best[4] = {1.0, 0.0, 0.0, 0.0};
    double bestn = -1.0;
    #pragma unroll
    for (int r = 0; r < 4; ++r) {
        int ri[3]; int t = 0;
        #pragma unroll
        for (int i = 0; i < 4; ++i) if (i != r) ri[t++] = i;
        double v[4];
        #pragma unroll
        for (int c = 0; c < 4; ++c) {
            int cj[3]; t = 0;
            #pragma unroll
            for (int j = 0; j < 4; ++j) if (j != c) cj[t++] = j;
            const double d = det3(K, ri[0],ri[1],ri[2], cj[0],cj[1],cj[2]);
            v[c] = ((r + c) & 1) ? -d : d;
        }
        const double n = v[0]*v[0]+v[1]*v[1]+v[2]*v[2]+v[3]*v[3];
        if (n > bestn) { bestn = n; best[0]=v[0]; best[1]=v[1]; best[2]=v[2]; best[3]=v[3]; }
    }
    const double qn = 1.0 / sqrt(bestn);
    const double q0d = best[0]*qn, qxd = best[1]*qn, qyd = best[2]*qn, qzd = best[3]*qn;

    const float R00 = (float)(q0d*q0d+qxd*qxd-qyd*qyd-qzd*qzd);
    const float R01 = (float)(2.0*(qxd*qyd - q0d*qzd));
    const float R02 = (float)(2.0*(qxd*qzd + q0d*qyd));
    const float R10 = (float)(2.0*(qyd*qxd + q0d*qzd));
    const float R11 = (float)(q0d*q0d-qxd*qxd+qyd*qyd-qzd*qzd);
    const float R12 = (float)(2.0*(qyd*qzd - q0d*qxd));
    const float R20 = (float)(2.0*(qzd*qxd - q0d*qyd));
    const float R21 = (float)(2.0*(qzd*qyd + q0d*qxd));
    const float R22 = (float)(q0d*q0d-qxd*qxd-qyd*qyd+qzd*qzd);

    double d0 = (Lt <= 15.0) ? 0.5 : (1.24 * cbrt(Lt - 15.0) - 1.8);
    if (d0 < 0.5) d0 = 0.5;
    const float inv_d0sq = (float)(1.0 / (d0 * d0));
    const float invLtf   = (float)invLt;
    const float pmx = (float)pmxd, pmy = (float)pmyd, pmz = (float)pmzd;
    const float tmx = (float)tmxd, tmy = (float)tmyd, tmz = (float)tmzd;

    // ---------------- Phase 2: aligned distances -> TM (LDS reuse) ----------------
    float tacc = 0.f;
    #pragma unroll
    for (int k = 0; k < 4; ++k) {
        const float4* rp = (const float4*)&ldsP[k * 3072 + tid * 12];
        const float4 q0 = rp[0], q1 = rp[1], q2 = rp[2];
        const float4 u0 = gt4[k * 768 + tid * 3 + 0];   // L2-resident re-read
        const float4 u1 = gt4[k * 768 + tid * 3 + 1];
        const float4 u2 = gt4[k * 768 + tid * 3 + 2];

        const float px[4] = {q0.x, q0.w, q1.z, q2.y};
        const float py[4] = {q0.y, q1.x, q1.w, q2.z};
        const float pz[4] = {q0.z, q1.y, q2.x, q2.w};
        const float tx[4] = {u0.x, u0.w, u1.z, u2.y};
        const float ty[4] = {u0.y, u1.x, u1.w, u2.z};
        const float tz[4] = {u0.z, u1.y, u2.x, u2.w};

        #pragma unroll
        for (int r = 0; r < 4; ++r) {
            const float w = ((mbits >> (k * 4 + r)) & 1u) ? 1.f : 0.f;
            const float vx = px[r] - pmx, vy = py[r] - pmy, vz = pz[r] - pmz;
            const float a0 = R00*vx + R01*vy + R02*vz + tmx - tx[r];
            const float a1 = R10*vx + R11*vy + R12*vz + tmy - ty[r];
            const float a2 = R20*vx + R21*vy + R22*vz + tmz - tz[r];
            const float dsq = a0*a0 + a1*a1 + a2*a2;
            tacc += w * __builtin_amdgcn_rcpf(1.0f + dsq * inv_d0sq);
        }
    }
    tacc *= invLtf;

    float r = waveReduceSum(tacc);
    if (lane == 0) sfin[wave] = r;
    __syncthreads();
    if (tid == 0)
        out[s] = sfin[0] + sfin[1] + sfin[2] + sfin[3];
}

extern "C" void kernel_launch(void* const* d_in, const int* in_sizes, int n_in,
                              void* d_out, int out_size, void* d_ws, size_t ws_size,
                              hipStream_t stream) {
    const float* pred = (const float*)d_in[0];
    const float* tru  = (const float*)d_in[1];
    const int*   mask = (const int*)d_in[2];
    float* out = (float*)d_out;
    (void)d_ws; (void)ws_size;
    tm_fused<<<NS, TPB, 0, stream>>>(pred, tru, mask, out);
}

// Round 2
// 97.499 us; speedup vs baseline: 1.1629x; 1.1629x over previous
//
#include <hip/hip_runtime.h>
#include <math.h>

// TM-score, single fused kernel. S=1024 samples, L=4096 residues, fp32.
// One block per sample, 256 threads, 16 residues/thread in 4 chunks.
// v3: Phase 1 identical to the proven round-0 kernel (LDS-staged coalesced
//     loads -> 18 covariance sums -> block reduce; QCP fp64 solve per-thread).
//     Phase 2 changed: NO LDS bounce, NO barriers -- per-thread direct global
//     reads of pred/true (L3/L1-warm after phase 1; stride-48B float4 triples
//     hit every 64B line on load 0, loads 1-2 are L1 hits). Mask carried
//     between phases as 16 register bits. Barriers 18 -> 10.

#define NS        1024
#define NL        4096
#define TPB       256
#define CHUNK_RES 1024
#define NCHUNK    4

__device__ __forceinline__ float waveReduceSum(float v) {
    #pragma unroll
    for (int off = 32; off > 0; off >>= 1)
        v += __shfl_down(v, off, 64);
    return v;
}

__device__ __forceinline__ double det3(const double B[4][4],
                                       int r0, int r1, int r2,
                                       int c0, int c1, int c2) {
    return B[r0][c0]*(B[r1][c1]*B[r2][c2] - B[r1][c2]*B[r2][c1])
         - B[r0][c1]*(B[r1][c0]*B[r2][c2] - B[r1][c2]*B[r2][c0])
         + B[r0][c2]*(B[r1][c0]*B[r2][c1] - B[r1][c1]*B[r2][c0]);
}

__global__ __launch_bounds__(TPB, 4) void tm_fused(
    const float* __restrict__ pred, const float* __restrict__ tru,
    const int* __restrict__ mask, float* __restrict__ out)
{
    const int s    = blockIdx.x;
    const int tid  = threadIdx.x;
    const int wave = tid >> 6, lane = tid & 63;
    const float* ps = pred + (size_t)s * NL * 3;

    __shared__ float ldsP[CHUNK_RES * 3];   // 12 KB
    __shared__ float ldsT[CHUNK_RES * 3];   // 12 KB
    __shared__ float sred[4][18];
    __shared__ float sfin[4];

    // acc: [0]=Lt [1..3]=St [4..6]=Sp [7..15]=C[i][j] [16]=Sum w|p|^2 [17]=Sum w|t|^2
    float acc[18];
    #pragma unroll
    for (int i = 0; i < 18; ++i) acc[i] = 0.f;

    unsigned mbits = 0;   // 16 residues/thread, 1 bit each, set in phase 1

    // ---------------- Phase 1: covariance sums (round-0 proven path) --------
    for (int k = 0; k < NCHUNK; ++k) {
        const float4* gp = (const float4*)(ps  + (size_t)k * CHUNK_RES * 3);
        const float4* gt = (const float4*)(tru + (size_t)k * CHUNK_RES * 3);
        float4* lp = (float4*)ldsP;
        float4* lt = (float4*)ldsT;
        #pragma unroll
        for (int j = 0; j < 3; ++j) {
            const int idx = wave * 192 + j * 64 + lane;   // coalesced 1KB/instr
            lp[idx] = gp[idx];
            lt[idx] = gt[idx];
        }
        __syncthreads();

        const float4* rp = (const float4*)&ldsP[tid * 12];
        const float4* rt = (const float4*)&ldsT[tid * 12];
        const float4 q0 = rp[0], q1 = rp[1], q2 = rp[2];
        const float4 u0 = rt[0], u1 = rt[1], u2 = rt[2];
        const int4   mi = *(const int4*)(mask + k * CHUNK_RES + tid * 4);

        const float px[4] = {q0.x, q0.w, q1.z, q2.y};
        const float py[4] = {q0.y, q1.x, q1.w, q2.z};
        const float pz[4] = {q0.z, q1.y, q2.x, q2.w};
        const float tx[4] = {u0.x, u0.w, u1.z, u2.y};
        const float ty[4] = {u0.y, u1.x, u1.w, u2.z};
        const float tz[4] = {u0.z, u1.y, u2.x, u2.w};
        const float wm[4] = {mi.x ? 1.f : 0.f, mi.y ? 1.f : 0.f,
                             mi.z ? 1.f : 0.f, mi.w ? 1.f : 0.f};
        if (mi.x) mbits |= 1u << (k * 4 + 0);
        if (mi.y) mbits |= 1u << (k * 4 + 1);
        if (mi.z) mbits |= 1u << (k * 4 + 2);
        if (mi.w) mbits |= 1u << (k * 4 + 3);

        #pragma unroll
        for (int r = 0; r < 4; ++r) {
            const float w = wm[r];
            const float wpx = w * px[r], wpy = w * py[r], wpz = w * pz[r];
            acc[0] += w;
            acc[1] += w * tx[r]; acc[2] += w * ty[r]; acc[3] += w * tz[r];
            acc[4] += wpx; acc[5] += wpy; acc[6] += wpz;
            acc[7]  += wpx * tx[r]; acc[8]  += wpx * ty[r]; acc[9]  += wpx * tz[r];
            acc[10] += wpy * tx[r]; acc[11] += wpy * ty[r]; acc[12] += wpy * tz[r];
            acc[13] += wpz * tx[r]; acc[14] += wpz * ty[r]; acc[15] += wpz * tz[r];
            acc[16] += wpx * px[r] + wpy * py[r] + wpz * pz[r];
            acc[17] += w * (tx[r]*tx[r] + ty[r]*ty[r] + tz[r]*tz[r]);
        }
        __syncthreads();   // before next chunk overwrites LDS
    }

    #pragma unroll
    for (int i = 0; i < 18; ++i) {
        float r = waveReduceSum(acc[i]);
        if (lane == 0) sred[wave][i] = r;
    }
    __syncthreads();

    // ---------------- QCP solve (all threads, identical data) ----------------
    double S[18];
    #pragma unroll
    for (int i = 0; i < 18; ++i)
        S[i] = (double)sred[0][i] + (double)sred[1][i]
             + (double)sred[2][i] + (double)sred[3][i];

    const double Lt = S[0], invLt = 1.0 / Lt;
    const double tmxd = S[1]*invLt, tmyd = S[2]*invLt, tmzd = S[3]*invLt;
    const double pmxd = S[4]*invLt, pmyd = S[5]*invLt, pmzd = S[6]*invLt;

    // scaled centered covariance HA = (C - Sp St^T / Lt) / Lt ; scaled Gram traces
    double HA[3][3];
    const double Sp[3] = {S[4], S[5], S[6]};
    const double St[3] = {S[1], S[2], S[3]};
    #pragma unroll
    for (int i = 0; i < 3; ++i)
        #pragma unroll
        for (int j = 0; j < 3; ++j)
            HA[i][j] = (S[7 + i*3 + j] - Sp[i]*St[j]*invLt) * invLt;
    const double gA = (S[16] - (Sp[0]*Sp[0]+Sp[1]*Sp[1]+Sp[2]*Sp[2])*invLt) * invLt;
    const double gB = (S[17] - (St[0]*St[0]+St[1]*St[1]+St[2]*St[2])*invLt) * invLt;

    const double Sxx=HA[0][0], Sxy=HA[0][1], Sxz=HA[0][2];
    const double Syx=HA[1][0], Syy=HA[1][1], Syz=HA[1][2];
    const double Szx=HA[2][0], Szy=HA[2][1], Szz=HA[2][2];
    double K[4][4] = {
      { Sxx+Syy+Szz, Syz-Szy,      Szx-Sxz,      Sxy-Syx      },
      { Syz-Szy,     Sxx-Syy-Szz,  Sxy+Syx,      Szx+Sxz      },
      { Szx-Sxz,     Sxy+Syx,      Syy-Sxx-Szz,  Syz+Szy      },
      { Sxy-Syx,     Szx+Sxz,      Syz+Szy,      Szz-Sxx-Syy  }
    };

    // char poly det(lam I - K) = lam^4 + E2 lam^2 - E3 lam + E4   (tr K = 0)
    double E2 = 0.0;
    #pragma unroll
    for (int i = 0; i < 4; ++i)
        #pragma unroll
        for (int j = 0; j < 4; ++j)
            if (j > i) E2 += K[i][i]*K[j][j] - K[i][j]*K[i][j];
    const double E3 = det3(K,1,2,3, 1,2,3) + det3(K,0,2,3, 0,2,3)
                    + det3(K,0,1,3, 0,1,3) + det3(K,0,1,2, 0,1,2);
    const double E4 = K[0][0]*det3(K,1,2,3, 1,2,3) - K[0][1]*det3(K,1,2,3, 0,2,3)
                    + K[0][2]*det3(K,1,2,3, 0,1,3) - K[0][3]*det3(K,1,2,3, 0,1,2);

    double lam = 0.5 * (gA + gB);          // upper bound on lambda_max
    #pragma unroll
    for (int it = 0; it < 8; ++it) {
        const double l2 = lam * lam;
        const double P  = ((l2 + E2) * lam - E3) * lam + E4;
        const double Pd = (4.0 * l2 + 2.0 * E2) * lam - E3;
        if (fabs(Pd) < 1e-300) break;
        lam -= P / Pd;
    }

    // eigenvector = best row of cofactor matrix of B = K - lam I
    #pragma unroll
    for (int i = 0; i < 4; ++i) K[i][i] -= lam;
    double best[4] = {1.0, 0.0, 0.0, 0.0};
    double bestn = -1.0;
    #pragma unroll
    for (int r = 0; r < 4; ++r) {
        int ri[3]; int t = 0;
        #pragma unroll
        for (int i = 0; i < 4; ++i) if (i != r) ri[t++] = i;
        double v[4];
        #pragma unroll
        for (int c = 0; c < 4; ++c) {
            int cj[3]; t = 0;
            #pragma unroll
            for (int j = 0; j < 4; ++j) if (j != c) cj[t++] = j;
            const double d = det3(K, ri[0],ri[1],ri[2], cj[0],cj[1],cj[2]);
            v[c] = ((r + c) & 1) ? -d : d;
        }
        const double n = v[0]*v[0]+v[1]*v[1]+v[2]*v[2]+v[3]*v[3];
        if (n > bestn) { bestn = n; best[0]=v[0]; best[1]=v[1]; best[2]=v[2]; best[3]=v[3]; }
    }
    const double qn = 1.0 / sqrt(bestn);
    const double q0d = best[0]*qn, qxd = best[1]*qn, qyd = best[2]*qn, qzd = best[3]*qn;

    const float R00 = (float)(q0d*q0d+qxd*qxd-qyd*qyd-qzd*qzd);
    const float R01 = (float)(2.0*(qxd*qyd - q0d*qzd));
    const float R02 = (float)(2.0*(qxd*qzd + q0d*qyd));
    const float R10 = (float)(2.0*(qyd*qxd + q0d*qzd));
    const float R11 = (float)(q0d*q0d-qxd*qxd+qyd*qyd-qzd*qzd);
    const float R12 = (float)(2.0*(qyd*qzd - q0d*qxd));
    const float R20 = (float)(2.0*(qzd*qxd - q0d*qyd));
    const float R21 = (float)(2.0*(qzd*qyd + q0d*qxd));
    const float R22 = (float)(q0d*q0d-qxd*qxd-qyd*qyd+qzd*qzd);

    double d0 = (Lt <= 15.0) ? 0.5 : (1.24 * cbrt(Lt - 15.0) - 1.8);
    if (d0 < 0.5) d0 = 0.5;
    const float inv_d0sq = (float)(1.0 / (d0 * d0));
    const float invLtf   = (float)invLt;
    const float pmx = (float)pmxd, pmy = (float)pmyd, pmz = (float)pmzd;
    const float tmx = (float)tmxd, tmy = (float)tmyd, tmz = (float)tmzd;

    // ------- Phase 2: aligned distances -> TM (direct global, no LDS) -------
    // Per thread: 3 pred float4 + 3 true float4 per chunk at stride 48B.
    // Load 0 of each triple pulls every 64B line of the wave's 3KB window
    // (pred is L3-resident after phase 1, true is L2-resident); loads 1-2
    // are L1 hits. No barriers in this phase.
    float tacc = 0.f;
    const float4* gt4 = (const float4*)tru;
    for (int k = 0; k < NCHUNK; ++k) {
        const float4* gp4 = (const float4*)(ps + (size_t)k * CHUNK_RES * 3);
        const int b = tid * 3;
        const float4 q0 = gp4[b + 0], q1 = gp4[b + 1], q2 = gp4[b + 2];
        const float4 u0 = gt4[k * 768 + b + 0];
        const float4 u1 = gt4[k * 768 + b + 1];
        const float4 u2 = gt4[k * 768 + b + 2];

        const float px[4] = {q0.x, q0.w, q1.z, q2.y};
        const float py[4] = {q0.y, q1.x, q1.w, q2.z};
        const float pz[4] = {q0.z, q1.y, q2.x, q2.w};
        const float tx[4] = {u0.x, u0.w, u1.z, u2.y};
        const float ty[4] = {u0.y, u1.x, u1.w, u2.z};
        const float tz[4] = {u0.z, u1.y, u2.x, u2.w};

        #pragma unroll
        for (int r = 0; r < 4; ++r) {
            const float w = ((mbits >> (k * 4 + r)) & 1u) ? 1.f : 0.f;
            const float vx = px[r] - pmx, vy = py[r] - pmy, vz = pz[r] - pmz;
            const float a0 = R00*vx + R01*vy + R02*vz + tmx - tx[r];
            const float a1 = R10*vx + R11*vy + R12*vz + tmy - ty[r];
            const float a2 = R20*vx + R21*vy + R22*vz + tmz - tz[r];
            const float dsq = a0*a0 + a1*a1 + a2*a2;
            tacc += w * __builtin_amdgcn_rcpf(1.0f + dsq * inv_d0sq);
        }
    }
    tacc *= invLtf;

    float r = waveReduceSum(tacc);
    if (lane == 0) sfin[wave] = r;
    __syncthreads();
    if (tid == 0)
        out[s] = sfin[0] + sfin[1] + sfin[2] + sfin[3];
}

extern "C" void kernel_launch(void* const* d_in, const int* in_sizes, int n_in,
                              void* d_out, int out_size, void* d_ws, size_t ws_size,
                              hipStream_t stream) {
    const float* pred = (const float*)d_in[0];
    const float* tru  = (const float*)d_in[1];
    const int*   mask = (const int*)d_in[2];
    float* out = (float*)d_out;
    (void)d_ws; (void)ws_size;
    tm_fused<<<NS, TPB, 0, stream>>>(pred, tru, mask, out);
}